// Round 11
// baseline (746.956 us; speedup 1.0000x reference)
//
#include <hip/hip_runtime.h>
#include <hip/hip_bf16.h>
#include <cmath>

// Problem dims (fixed): B=16, T=1024, IN=1024, H=1024
// M = B*T = 16384, K1 = 1024, N1 = 1024, K2 = 2048, N2 = 1024
//
// Numerics contract (validated round 5): GEMM1 must be a sequential
// ascending-k f32 FMA chain per output element + separate f32 bias add
// (mirrors the np golden's BLAS sgemm). Scan mirrors numpy f32 op-for-op.
// GEMM2 (smooth tanh) is bf16 MFMA.
//
// Round 11: gemm1 BLOCKING change (not scheduling -- r7/r9 lesson): same
// 128x128 tile & LDS, but 128 threads x (16x8 outputs)/thread. LDS-read
// instructions per FMA drop 25% (24 b128 per 512 FMAs vs 16 per 256); the
// LDS pipe, not the VALU, was the structural limit of 8x8 blocking.
// Risk: ~240 VGPR (spill watch via VGPR_Count). Tail unchanged from r10.

typedef __attribute__((ext_vector_type(8))) __bf16 bf16x8;
typedef __attribute__((ext_vector_type(4))) __bf16 bf16x4;
typedef __attribute__((ext_vector_type(4))) float  f32x4;

#define LDT 40  // bf16 LDS pad (GEMM2): 80B rows
#define LDF 36  // f32 LDS pad (GEMM1): 144B rows — measured 0 bank conflicts

// ---------------------------------------------------------------------------
// GEMM1 (f32 FMA-chain): I[m,h] = fadd( fmaf-chain_{k=0..1023}, b_in[h] )
// 128 threads as 16(tx) x 8(ty): thread owns rows {ty+8i? no:} rows ty+16i
// NOTE mapping: ty in 0..7 -> rows ty*? We use rows (ty + 8*i)? Keep simple:
// rows = ty + 8*i for i<16 (covers 0..127), cols = tx + 16*j for j<8.
// ---------------------------------------------------------------------------
__global__ __launch_bounds__(128, 2)
void gemm1_f32chain_kernel(const float* __restrict__ X,
                           const float* __restrict__ W,
                           const float* __restrict__ bias,
                           float* __restrict__ I)
{
    __shared__ __align__(16) float sA[128][LDF];
    __shared__ __align__(16) float sB[128][LDF];

    const int tid  = threadIdx.x;     // 0..127
    const int bn   = blockIdx.x;      // 0..7
    const int bm   = blockIdx.y;      // 0..127
    const int row0 = bm * 128;
    const int col0 = bn * 128;
    const int tx   = tid & 15;        // 0..15
    const int ty   = tid >> 4;        // 0..7

    float acc[16][8];
    #pragma unroll
    for (int i = 0; i < 16; ++i)
        #pragma unroll
        for (int j = 0; j < 8; ++j)
            acc[i][j] = 0.0f;

    for (int k0 = 0; k0 < 1024; k0 += 32) {
        // stage 128x32 f32 tiles: 8 f32x4 chunks per matrix per thread
        #pragma unroll
        for (int i = 0; i < 8; ++i) {
            int q  = tid + i * 128;   // 0..1023
            int r  = q >> 3;          // 0..127
            int c4 = (q & 7) * 4;     // 0..28
            *(f32x4*)&sA[r][c4] = *(const f32x4*)&X[(size_t)(row0 + r) * 1024 + k0 + c4];
            *(f32x4*)&sB[r][c4] = *(const f32x4*)&W[(size_t)(col0 + r) * 1024 + k0 + c4];
        }
        __syncthreads();

        // FMA order strictly ascending k (kk group asc, q asc within group)
        #pragma unroll
        for (int kk = 0; kk < 32; kk += 4) {
            f32x4 a4[16], b4[8];
            #pragma unroll
            for (int i = 0; i < 16; ++i) a4[i] = *(const f32x4*)&sA[ty + 8 * i][kk];
            #pragma unroll
            for (int j = 0; j < 8; ++j)  b4[j] = *(const f32x4*)&sB[tx + 16 * j][kk];
            #pragma unroll
            for (int q = 0; q < 4; ++q)
                #pragma unroll
                for (int i = 0; i < 16; ++i)
                    #pragma unroll
                    for (int j = 0; j < 8; ++j)
                        acc[i][j] = fmaf(a4[i][q], b4[j][q], acc[i][j]);
        }
        __syncthreads();
    }

    #pragma unroll
    for (int i = 0; i < 16; ++i)
        #pragma unroll
        for (int j = 0; j < 8; ++j) {
            int rg = row0 + ty + 8 * i;
            int cg = col0 + tx + 16 * j;
            I[(size_t)rg * 1024 + cg] = __fadd_rn(acc[i][j], bias[cg]);
        }
}

// ---------------------------------------------------------------------------
// Scan, numpy-f32 mirror (validated):
//   alpha = expf(-logaddexpf(lt,0)) via round-to-f32 of f64 libm
//   v = fadd(fmul(alpha, v), I); spike = v > thr; v = fmul(v, 1-spike)
// 16-deep static prefetch ring; 1 wave per block, 256 blocks (all CUs busy).
// ---------------------------------------------------------------------------
__global__ __launch_bounds__(64)
void hsru_scan_f32_kernel(const float* __restrict__ I,
                          const float* __restrict__ leak,
                          const float* __restrict__ thr,
                          __bf16* __restrict__ comb)
{
    int g = blockIdx.x * 64 + threadIdx.x;  // 0..16383
    int b = g >> 10;
    int h = g & 1023;

    float lt = leak[h];
    float e     = (float)exp(-(double)fabsf(lt));
    float l1    = (float)log1p((double)e);
    float sp    = __fadd_rn(fmaxf(lt, 0.0f), l1);
    float alpha = (float)exp(-(double)sp);
    float th    = thr[h];

    const float* Ip = I    + (size_t)b * (1024 * 1024) + h;
    __bf16*      cp = comb + (size_t)b * (1024 * 2048) + h;

    float buf[16], nxt[16];
    #pragma unroll
    for (int j = 0; j < 16; ++j) buf[j] = Ip[(size_t)j * 1024];

    float v = 0.0f;
    for (int t0 = 0; t0 < 1024; t0 += 16) {
        if (t0 + 16 < 1024) {
            #pragma unroll
            for (int j = 0; j < 16; ++j)
                nxt[j] = Ip[(size_t)(t0 + 16 + j) * 1024];
        }
        #pragma unroll
        for (int j = 0; j < 16; ++j) {
            float cur = buf[j];
            v = __fadd_rn(__fmul_rn(alpha, v), cur);
            float spike = (v > th) ? 1.0f : 0.0f;
            v = __fmul_rn(v, __fsub_rn(1.0f, spike));
            cp[(size_t)(t0 + j) * 2048]        = (__bf16)v;
            cp[(size_t)(t0 + j) * 2048 + 1024] = (__bf16)spike;
        }
        if (t0 + 16 < 1024) {
            #pragma unroll
            for (int j = 0; j < 16; ++j) buf[j] = nxt[j];
        }
    }
}

// ---------------------------------------------------------------------------
// W_out f32 -> bf16 pre-convert (once per launch; 2M elements)
// ---------------------------------------------------------------------------
__global__ __launch_bounds__(256)
void wcvt_kernel(const float* __restrict__ W, __bf16* __restrict__ Wb)
{
    int idx = (blockIdx.x * 256 + threadIdx.x) * 8;   // 8 elements/thread
    f32x4 v0 = *(const f32x4*)&W[idx];
    f32x4 v1 = *(const f32x4*)&W[idx + 4];
    bf16x8 o;
    #pragma unroll
    for (int j = 0; j < 4; ++j) { o[j] = (__bf16)v0[j]; o[4 + j] = (__bf16)v1[j]; }
    *(bf16x8*)&Wb[idx] = o;
}

// ---------------------------------------------------------------------------
// GEMM2: out = tanh(combined @ Wb^T + b_out), bf16 MFMA (smooth path).
// A = comb [M,2048] bf16, B = Wb [1024,2048] bf16 (pre-converted)
// ---------------------------------------------------------------------------
__global__ __launch_bounds__(256)
void gemm2_kernel(const __bf16* __restrict__ A,
                  const __bf16* __restrict__ Wb,
                  const float* __restrict__ bias,
                  float* __restrict__ O)
{
    __shared__ __align__(16) __bf16 sA[128][LDT];
    __shared__ __align__(16) __bf16 sB[128][LDT];

    const int tid  = threadIdx.x;
    const int bn   = blockIdx.x;
    const int bm   = blockIdx.y;
    const int row0 = bm * 128;
    const int col0 = bn * 128;

    const int lane = tid & 63;
    const int wid  = tid >> 6;
    const int wm   = (wid >> 1) * 64;
    const int wn   = (wid & 1) * 64;

    f32x4 acc[4][4];
    #pragma unroll
    for (int i = 0; i < 4; ++i)
        #pragma unroll
        for (int j = 0; j < 4; ++j)
            acc[i][j] = f32x4{0.f, 0.f, 0.f, 0.f};

    const int frow  = lane & 15;
    const int fkoff = (lane >> 4) * 8;

    for (int k0 = 0; k0 < 2048; k0 += 32) {
        #pragma unroll
        for (int i = 0; i < 2; ++i) {
            int q  = tid + i * 256;   // 0..511
            int r  = q >> 2;          // 0..127
            int c8 = (q & 3) * 8;     // 0..24
            *(bf16x8*)&sA[r][c8] = *(const bf16x8*)&A [(size_t)(row0 + r) * 2048 + k0 + c8];
            *(bf16x8*)&sB[r][c8] = *(const bf16x8*)&Wb[(size_t)(col0 + r) * 2048 + k0 + c8];
        }
        __syncthreads();

        bf16x8 a_f[4], b_f[4];
        #pragma unroll
        for (int f = 0; f < 4; ++f) {
            a_f[f] = *(const bf16x8*)&sA[wm + f * 16 + frow][fkoff];
            b_f[f] = *(const bf16x8*)&sB[wn + f * 16 + frow][fkoff];
        }
        #pragma unroll
        for (int fm = 0; fm < 4; ++fm)
            #pragma unroll
            for (int fn = 0; fn < 4; ++fn)
                acc[fm][fn] = __builtin_amdgcn_mfma_f32_16x16x32_bf16(a_f[fm], b_f[fn], acc[fm][fn], 0, 0, 0);
        __syncthreads();
    }

    const int crow = (lane >> 4) * 4;
    const int ccol = lane & 15;
    #pragma unroll
    for (int fm = 0; fm < 4; ++fm)
        #pragma unroll
        for (int fn = 0; fn < 4; ++fn)
            #pragma unroll
            for (int j = 0; j < 4; ++j) {
                int rg = row0 + wm + fm * 16 + crow + j;
                int cg = col0 + wn + fn * 16 + ccol;
                O[(size_t)rg * 1024 + cg] = tanhf(acc[fm][fn][j] + bias[cg]);
            }
}

// ---------------------------------------------------------------------------
extern "C" void kernel_launch(void* const* d_in, const int* in_sizes, int n_in,
                              void* d_out, int out_size, void* d_ws, size_t ws_size,
                              hipStream_t stream)
{
    const float* x     = (const float*)d_in[0];
    const float* W_in  = (const float*)d_in[1];
    const float* b_in  = (const float*)d_in[2];
    const float* leak  = (const float*)d_in[3];
    const float* thr   = (const float*)d_in[4];
    const float* W_out = (const float*)d_in[5];
    const float* b_out = (const float*)d_in[6];

    // ws: [0,64MiB) comb bf16 ; [64MiB, 64MiB+4MiB) Wb bf16
    const size_t NEED = (64ull << 20) + (4ull << 20);
    if (ws_size < NEED) return;

    float*  out  = (float*)d_out;   // also I scratch
    __bf16* comb = (__bf16*)d_ws;
    __bf16* Wb   = (__bf16*)((char*)d_ws + (64ull << 20));

    dim3 grid(8, 128);

    wcvt_kernel<<<1024, 256, 0, stream>>>(W_out, Wb);
    gemm1_f32chain_kernel<<<grid, 128, 0, stream>>>(x, W_in, b_in, out);
    hsru_scan_f32_kernel<<<256, 64, 0, stream>>>(out, leak, thr, comb);
    gemm2_kernel<<<grid, 256, 0, stream>>>(comb, Wb, b_out, out);
}

// Round 12
// 577.560 us; speedup vs baseline: 1.2933x; 1.2933x over previous
//
#include <hip/hip_runtime.h>
#include <hip/hip_bf16.h>
#include <cmath>

// Problem dims (fixed): B=16, T=1024, IN=1024, H=1024
// M = B*T = 16384, K1 = 1024, N1 = 1024, K2 = 2048, N2 = 1024
//
// Numerics contract (validated round 5): GEMM1 must be a sequential
// ascending-k f32 FMA chain per output element + separate f32 bias add
// (mirrors the np golden's BLAS sgemm). Scan mirrors numpy f32 op-for-op.
// GEMM2 (smooth tanh) is bf16 MFMA.
//
// Round 12: gemm1 PACKED-FP32 FMA (v_pk_fma_f32 via f32x2 +
// __builtin_elementwise_fma). Packing is across OUTPUT PAIRS (rows 2i2,
// 2i2+1), never across k: each output keeps its bit-exact sequential
// ascending-k IEEE FMA chain (pk_fma = two independent fp32 FMAs).
// Staging/LDS identical to r10 (LDF=36, measured 0 conflicts, VGPR 104
// structure). r11's 16x8 blocking spilled (WRITE_SIZE 65->662MB) - closed.

typedef __attribute__((ext_vector_type(8))) __bf16 bf16x8;
typedef __attribute__((ext_vector_type(4))) __bf16 bf16x4;
typedef __attribute__((ext_vector_type(4))) float  f32x4;
typedef __attribute__((ext_vector_type(2))) float  f32x2;

#define LDT 40  // bf16 LDS pad (GEMM2): 80B rows
#define LDF 36  // f32 LDS pad (GEMM1): 144B rows — measured 0 bank conflicts

// ---------------------------------------------------------------------------
// GEMM1 (f32 FMA-chain): I[m,h] = fadd( fmaf-chain_{k=0..1023}, b_in[h] )
// ---------------------------------------------------------------------------
__global__ __launch_bounds__(256)
void gemm1_f32chain_kernel(const float* __restrict__ X,
                           const float* __restrict__ W,
                           const float* __restrict__ bias,
                           float* __restrict__ I)
{
    __shared__ __align__(16) float sA[128][LDF];
    __shared__ __align__(16) float sB[128][LDF];

    const int tid  = threadIdx.x;
    const int bn   = blockIdx.x;      // 0..7
    const int bm   = blockIdx.y;      // 0..127
    const int row0 = bm * 128;
    const int col0 = bn * 128;
    const int tx   = tid & 15;
    const int ty   = tid >> 4;

    // acc2[i2][j]: lo half = row ty+16*(2*i2), hi half = row ty+16*(2*i2+1)
    f32x2 acc2[4][8];
    #pragma unroll
    for (int i = 0; i < 4; ++i)
        #pragma unroll
        for (int j = 0; j < 8; ++j)
            acc2[i][j] = f32x2{0.f, 0.f};

    for (int k0 = 0; k0 < 1024; k0 += 32) {
        #pragma unroll
        for (int i = 0; i < 4; ++i) {
            int q  = tid + i * 256;   // 0..1023
            int r  = q >> 3;          // 0..127
            int c4 = (q & 7) * 4;     // 0..28
            *(f32x4*)&sA[r][c4] = *(const f32x4*)&X[(size_t)(row0 + r) * 1024 + k0 + c4];
            *(f32x4*)&sB[r][c4] = *(const f32x4*)&W[(size_t)(col0 + r) * 1024 + k0 + c4];
        }
        __syncthreads();

        // ds_read_b128 x16 per 4-k group (unchanged). FMA order strictly
        // ascending k (kk group asc, q asc within it); one FMA per k per
        // output; pk packs output-pairs, not k.
        #pragma unroll
        for (int kk = 0; kk < 32; kk += 4) {
            f32x4 a4[8], b4[8];
            #pragma unroll
            for (int i = 0; i < 8; ++i) a4[i] = *(const f32x4*)&sA[ty + 16 * i][kk];
            #pragma unroll
            for (int j = 0; j < 8; ++j) b4[j] = *(const f32x4*)&sB[tx + 16 * j][kk];
            #pragma unroll
            for (int q = 0; q < 4; ++q) {
                f32x2 a2[4];
                #pragma unroll
                for (int i2 = 0; i2 < 4; ++i2)
                    a2[i2] = f32x2{a4[2 * i2][q], a4[2 * i2 + 1][q]};
                #pragma unroll
                for (int j = 0; j < 8; ++j) {
                    const float bv = b4[j][q];
                    const f32x2 b2 = f32x2{bv, bv};
                    #pragma unroll
                    for (int i2 = 0; i2 < 4; ++i2)
                        acc2[i2][j] = __builtin_elementwise_fma(a2[i2], b2, acc2[i2][j]);
                }
            }
        }
        __syncthreads();
    }

    #pragma unroll
    for (int i2 = 0; i2 < 4; ++i2)
        #pragma unroll
        for (int h = 0; h < 2; ++h)
            #pragma unroll
            for (int j = 0; j < 8; ++j) {
                int rg = row0 + ty + 16 * (2 * i2 + h);
                int cg = col0 + tx + 16 * j;
                I[(size_t)rg * 1024 + cg] = __fadd_rn(acc2[i2][j][h], bias[cg]);
            }
}

// ---------------------------------------------------------------------------
// Scan, numpy-f32 mirror (validated):
//   alpha = expf(-logaddexpf(lt,0)) via round-to-f32 of f64 libm
//   v = fadd(fmul(alpha, v), I); spike = v > thr; v = fmul(v, 1-spike)
// 16-deep static prefetch ring; 1 wave per block, 256 blocks (all CUs busy).
// ---------------------------------------------------------------------------
__global__ __launch_bounds__(64)
void hsru_scan_f32_kernel(const float* __restrict__ I,
                          const float* __restrict__ leak,
                          const float* __restrict__ thr,
                          __bf16* __restrict__ comb)
{
    int g = blockIdx.x * 64 + threadIdx.x;  // 0..16383
    int b = g >> 10;
    int h = g & 1023;

    float lt = leak[h];
    float e     = (float)exp(-(double)fabsf(lt));
    float l1    = (float)log1p((double)e);
    float sp    = __fadd_rn(fmaxf(lt, 0.0f), l1);
    float alpha = (float)exp(-(double)sp);
    float th    = thr[h];

    const float* Ip = I    + (size_t)b * (1024 * 1024) + h;
    __bf16*      cp = comb + (size_t)b * (1024 * 2048) + h;

    float buf[16], nxt[16];
    #pragma unroll
    for (int j = 0; j < 16; ++j) buf[j] = Ip[(size_t)j * 1024];

    float v = 0.0f;
    for (int t0 = 0; t0 < 1024; t0 += 16) {
        if (t0 + 16 < 1024) {
            #pragma unroll
            for (int j = 0; j < 16; ++j)
                nxt[j] = Ip[(size_t)(t0 + 16 + j) * 1024];
        }
        #pragma unroll
        for (int j = 0; j < 16; ++j) {
            float cur = buf[j];
            v = __fadd_rn(__fmul_rn(alpha, v), cur);
            float spike = (v > th) ? 1.0f : 0.0f;
            v = __fmul_rn(v, __fsub_rn(1.0f, spike));
            cp[(size_t)(t0 + j) * 2048]        = (__bf16)v;
            cp[(size_t)(t0 + j) * 2048 + 1024] = (__bf16)spike;
        }
        if (t0 + 16 < 1024) {
            #pragma unroll
            for (int j = 0; j < 16; ++j) buf[j] = nxt[j];
        }
    }
}

// ---------------------------------------------------------------------------
// W_out f32 -> bf16 pre-convert (once per launch; 2M elements)
// ---------------------------------------------------------------------------
__global__ __launch_bounds__(256)
void wcvt_kernel(const float* __restrict__ W, __bf16* __restrict__ Wb)
{
    int idx = (blockIdx.x * 256 + threadIdx.x) * 8;   // 8 elements/thread
    f32x4 v0 = *(const f32x4*)&W[idx];
    f32x4 v1 = *(const f32x4*)&W[idx + 4];
    bf16x8 o;
    #pragma unroll
    for (int j = 0; j < 4; ++j) { o[j] = (__bf16)v0[j]; o[4 + j] = (__bf16)v1[j]; }
    *(bf16x8*)&Wb[idx] = o;
}

// ---------------------------------------------------------------------------
// GEMM2: out = tanh(combined @ Wb^T + b_out), bf16 MFMA (smooth path).
// A = comb [M,2048] bf16, B = Wb [1024,2048] bf16 (pre-converted)
// ---------------------------------------------------------------------------
__global__ __launch_bounds__(256)
void gemm2_kernel(const __bf16* __restrict__ A,
                  const __bf16* __restrict__ Wb,
                  const float* __restrict__ bias,
                  float* __restrict__ O)
{
    __shared__ __align__(16) __bf16 sA[128][LDT];
    __shared__ __align__(16) __bf16 sB[128][LDT];

    const int tid  = threadIdx.x;
    const int bn   = blockIdx.x;
    const int bm   = blockIdx.y;
    const int row0 = bm * 128;
    const int col0 = bn * 128;

    const int lane = tid & 63;
    const int wid  = tid >> 6;
    const int wm   = (wid >> 1) * 64;
    const int wn   = (wid & 1) * 64;

    f32x4 acc[4][4];
    #pragma unroll
    for (int i = 0; i < 4; ++i)
        #pragma unroll
        for (int j = 0; j < 4; ++j)
            acc[i][j] = f32x4{0.f, 0.f, 0.f, 0.f};

    const int frow  = lane & 15;
    const int fkoff = (lane >> 4) * 8;

    for (int k0 = 0; k0 < 2048; k0 += 32) {
        #pragma unroll
        for (int i = 0; i < 2; ++i) {
            int q  = tid + i * 256;   // 0..511
            int r  = q >> 2;          // 0..127
            int c8 = (q & 3) * 8;     // 0..24
            *(bf16x8*)&sA[r][c8] = *(const bf16x8*)&A [(size_t)(row0 + r) * 2048 + k0 + c8];
            *(bf16x8*)&sB[r][c8] = *(const bf16x8*)&Wb[(size_t)(col0 + r) * 2048 + k0 + c8];
        }
        __syncthreads();

        bf16x8 a_f[4], b_f[4];
        #pragma unroll
        for (int f = 0; f < 4; ++f) {
            a_f[f] = *(const bf16x8*)&sA[wm + f * 16 + frow][fkoff];
            b_f[f] = *(const bf16x8*)&sB[wn + f * 16 + frow][fkoff];
        }
        #pragma unroll
        for (int fm = 0; fm < 4; ++fm)
            #pragma unroll
            for (int fn = 0; fn < 4; ++fn)
                acc[fm][fn] = __builtin_amdgcn_mfma_f32_16x16x32_bf16(a_f[fm], b_f[fn], acc[fm][fn], 0, 0, 0);
        __syncthreads();
    }

    const int crow = (lane >> 4) * 4;
    const int ccol = lane & 15;
    #pragma unroll
    for (int fm = 0; fm < 4; ++fm)
        #pragma unroll
        for (int fn = 0; fn < 4; ++fn)
            #pragma unroll
            for (int j = 0; j < 4; ++j) {
                int rg = row0 + wm + fm * 16 + crow + j;
                int cg = col0 + wn + fn * 16 + ccol;
                O[(size_t)rg * 1024 + cg] = tanhf(acc[fm][fn][j] + bias[cg]);
            }
}

// ---------------------------------------------------------------------------
extern "C" void kernel_launch(void* const* d_in, const int* in_sizes, int n_in,
                              void* d_out, int out_size, void* d_ws, size_t ws_size,
                              hipStream_t stream)
{
    const float* x     = (const float*)d_in[0];
    const float* W_in  = (const float*)d_in[1];
    const float* b_in  = (const float*)d_in[2];
    const float* leak  = (const float*)d_in[3];
    const float* thr   = (const float*)d_in[4];
    const float* W_out = (const float*)d_in[5];
    const float* b_out = (const float*)d_in[6];

    // ws: [0,64MiB) comb bf16 ; [64MiB, 64MiB+4MiB) Wb bf16
    const size_t NEED = (64ull << 20) + (4ull << 20);
    if (ws_size < NEED) return;

    float*  out  = (float*)d_out;   // also I scratch
    __bf16* comb = (__bf16*)d_ws;
    __bf16* Wb   = (__bf16*)((char*)d_ws + (64ull << 20));

    dim3 grid(8, 128);

    wcvt_kernel<<<1024, 256, 0, stream>>>(W_out, Wb);
    gemm1_f32chain_kernel<<<grid, 256, 0, stream>>>(x, W_in, b_in, out);
    hsru_scan_f32_kernel<<<256, 64, 0, stream>>>(out, leak, thr, comb);
    gemm2_kernel<<<grid, 256, 0, stream>>>(comb, Wb, b_out, out);
}

// Round 13
// 569.298 us; speedup vs baseline: 1.3121x; 1.0145x over previous
//
#include <hip/hip_runtime.h>
#include <hip/hip_bf16.h>
#include <cmath>

// Problem dims (fixed): B=16, T=1024, IN=1024, H=1024
// M = B*T = 16384, K1 = 1024, N1 = 1024, K2 = 2048, N2 = 1024
//
// Numerics contract (validated round 5): GEMM1 must be a sequential
// ascending-k f32 FMA chain per output element + separate f32 bias add
// (mirrors the np golden's BLAS sgemm). Scan mirrors numpy f32 op-for-op.
// GEMM2 (smooth tanh) is bf16 MFMA.
//
// Round 13: gemm1 inner product via INLINE-ASM v_pk_fma_f32 (VOP3P).
// r12 proved __builtin_elementwise_fma scalarizes; hand asm is required.
//  - packing across OUTPUT ROW-PAIRS (rows ty+16*2p / ty+16*(2p+1)); each
//    output keeps its bit-exact sequential ascending-k IEEE chain (pk_fma
//    = two independent fp32 FMAs; op_sel broadcasts the shared b scalar).
//  - LDS layout & staging byte-identical to r10 (LDF=36, 0 conflicts).
//  - b loaded as two f32x2 halves (adjacent; merge-friendly); a-pairs
//    built in C from the b128-read f32x4s.

typedef __attribute__((ext_vector_type(8))) __bf16 bf16x8;
typedef __attribute__((ext_vector_type(4))) __bf16 bf16x4;
typedef __attribute__((ext_vector_type(4))) float  f32x4;
typedef __attribute__((ext_vector_type(2))) float  f32x2;

#define LDT 40  // bf16 LDS pad (GEMM2): 80B rows
#define LDF 36  // f32 LDS pad (GEMM1): 144B rows — measured 0 bank conflicts

// d.lo = a.lo*b.lo + d.lo ; d.hi = a.hi*b.lo + d.hi   (broadcast b.lo)
#define PK_FMA_BLO(d, a, b) \
    asm("v_pk_fma_f32 %0, %1, %2, %0 op_sel:[0,0,0] op_sel_hi:[1,0,1]" \
        : "+v"(d) : "v"(a), "v"(b))
// d.lo = a.lo*b.hi + d.lo ; d.hi = a.hi*b.hi + d.hi   (broadcast b.hi)
#define PK_FMA_BHI(d, a, b) \
    asm("v_pk_fma_f32 %0, %1, %2, %0 op_sel:[0,1,0] op_sel_hi:[1,1,1]" \
        : "+v"(d) : "v"(a), "v"(b))

// ---------------------------------------------------------------------------
// GEMM1 (f32 FMA-chain): I[m,h] = fadd( fmaf-chain_{k=0..1023}, b_in[h] )
// ---------------------------------------------------------------------------
__global__ __launch_bounds__(256)
void gemm1_f32chain_kernel(const float* __restrict__ X,
                           const float* __restrict__ W,
                           const float* __restrict__ bias,
                           float* __restrict__ I)
{
    __shared__ __align__(16) float sA[128][LDF];
    __shared__ __align__(16) float sB[128][LDF];

    const int tid  = threadIdx.x;
    const int bn   = blockIdx.x;      // 0..7
    const int bm   = blockIdx.y;      // 0..127
    const int row0 = bm * 128;
    const int col0 = bn * 128;
    const int tx   = tid & 15;
    const int ty   = tid >> 4;

    // acc2[p][j]: lo = row ty+16*(2p), hi = row ty+16*(2p+1), col tx+16*j
    f32x2 acc2[4][8];
    #pragma unroll
    for (int p = 0; p < 4; ++p)
        #pragma unroll
        for (int j = 0; j < 8; ++j)
            acc2[p][j] = f32x2{0.f, 0.f};

    for (int k0 = 0; k0 < 1024; k0 += 32) {
        #pragma unroll
        for (int i = 0; i < 4; ++i) {
            int q  = tid + i * 256;   // 0..1023
            int r  = q >> 3;          // 0..127
            int c4 = (q & 7) * 4;     // 0..28
            *(f32x4*)&sA[r][c4] = *(const f32x4*)&X[(size_t)(row0 + r) * 1024 + k0 + c4];
            *(f32x4*)&sB[r][c4] = *(const f32x4*)&W[(size_t)(col0 + r) * 1024 + k0 + c4];
        }
        __syncthreads();

        // FMA order per output: kk group ascending, q ascending within group
        // (enforced by the acc2 dependence chain); k = k0+kk+q strictly asc.
        #pragma unroll
        for (int kk = 0; kk < 32; kk += 4) {
            f32x4 a4[8];
            f32x2 b01[8], b23[8];
            #pragma unroll
            for (int i = 0; i < 8; ++i) a4[i] = *(const f32x4*)&sA[ty + 16 * i][kk];
            #pragma unroll
            for (int j = 0; j < 8; ++j) {
                b01[j] = *(const f32x2*)&sB[tx + 16 * j][kk];
                b23[j] = *(const f32x2*)&sB[tx + 16 * j][kk + 2];
            }
            #pragma unroll
            for (int q = 0; q < 4; ++q) {
                f32x2 a2[4];
                #pragma unroll
                for (int p = 0; p < 4; ++p)
                    a2[p] = f32x2{a4[2 * p][q], a4[2 * p + 1][q]};
                #pragma unroll
                for (int j = 0; j < 8; ++j) {
                    #pragma unroll
                    for (int p = 0; p < 4; ++p) {
                        if (q == 0)      PK_FMA_BLO(acc2[p][j], a2[p], b01[j]);
                        else if (q == 1) PK_FMA_BHI(acc2[p][j], a2[p], b01[j]);
                        else if (q == 2) PK_FMA_BLO(acc2[p][j], a2[p], b23[j]);
                        else             PK_FMA_BHI(acc2[p][j], a2[p], b23[j]);
                    }
                }
            }
        }
        __syncthreads();
    }

    #pragma unroll
    for (int p = 0; p < 4; ++p)
        #pragma unroll
        for (int h = 0; h < 2; ++h)
            #pragma unroll
            for (int j = 0; j < 8; ++j) {
                int rg = row0 + ty + 16 * (2 * p + h);
                int cg = col0 + tx + 16 * j;
                I[(size_t)rg * 1024 + cg] = __fadd_rn(acc2[p][j][h], bias[cg]);
            }
}

// ---------------------------------------------------------------------------
// Scan, numpy-f32 mirror (validated):
//   alpha = expf(-logaddexpf(lt,0)) via round-to-f32 of f64 libm
//   v = fadd(fmul(alpha, v), I); spike = v > thr; v = fmul(v, 1-spike)
// 16-deep static prefetch ring; 1 wave per block, 256 blocks (all CUs busy).
// ---------------------------------------------------------------------------
__global__ __launch_bounds__(64)
void hsru_scan_f32_kernel(const float* __restrict__ I,
                          const float* __restrict__ leak,
                          const float* __restrict__ thr,
                          __bf16* __restrict__ comb)
{
    int g = blockIdx.x * 64 + threadIdx.x;  // 0..16383
    int b = g >> 10;
    int h = g & 1023;

    float lt = leak[h];
    float e     = (float)exp(-(double)fabsf(lt));
    float l1    = (float)log1p((double)e);
    float sp    = __fadd_rn(fmaxf(lt, 0.0f), l1);
    float alpha = (float)exp(-(double)sp);
    float th    = thr[h];

    const float* Ip = I    + (size_t)b * (1024 * 1024) + h;
    __bf16*      cp = comb + (size_t)b * (1024 * 2048) + h;

    float buf[16], nxt[16];
    #pragma unroll
    for (int j = 0; j < 16; ++j) buf[j] = Ip[(size_t)j * 1024];

    float v = 0.0f;
    for (int t0 = 0; t0 < 1024; t0 += 16) {
        if (t0 + 16 < 1024) {
            #pragma unroll
            for (int j = 0; j < 16; ++j)
                nxt[j] = Ip[(size_t)(t0 + 16 + j) * 1024];
        }
        #pragma unroll
        for (int j = 0; j < 16; ++j) {
            float cur = buf[j];
            v = __fadd_rn(__fmul_rn(alpha, v), cur);
            float spike = (v > th) ? 1.0f : 0.0f;
            v = __fmul_rn(v, __fsub_rn(1.0f, spike));
            cp[(size_t)(t0 + j) * 2048]        = (__bf16)v;
            cp[(size_t)(t0 + j) * 2048 + 1024] = (__bf16)spike;
        }
        if (t0 + 16 < 1024) {
            #pragma unroll
            for (int j = 0; j < 16; ++j) buf[j] = nxt[j];
        }
    }
}

// ---------------------------------------------------------------------------
// W_out f32 -> bf16 pre-convert (once per launch; 2M elements)
// ---------------------------------------------------------------------------
__global__ __launch_bounds__(256)
void wcvt_kernel(const float* __restrict__ W, __bf16* __restrict__ Wb)
{
    int idx = (blockIdx.x * 256 + threadIdx.x) * 8;   // 8 elements/thread
    f32x4 v0 = *(const f32x4*)&W[idx];
    f32x4 v1 = *(const f32x4*)&W[idx + 4];
    bf16x8 o;
    #pragma unroll
    for (int j = 0; j < 4; ++j) { o[j] = (__bf16)v0[j]; o[4 + j] = (__bf16)v1[j]; }
    *(bf16x8*)&Wb[idx] = o;
}

// ---------------------------------------------------------------------------
// GEMM2: out = tanh(combined @ Wb^T + b_out), bf16 MFMA (smooth path).
// A = comb [M,2048] bf16, B = Wb [1024,2048] bf16 (pre-converted)
// ---------------------------------------------------------------------------
__global__ __launch_bounds__(256)
void gemm2_kernel(const __bf16* __restrict__ A,
                  const __bf16* __restrict__ Wb,
                  const float* __restrict__ bias,
                  float* __restrict__ O)
{
    __shared__ __align__(16) __bf16 sA[128][LDT];
    __shared__ __align__(16) __bf16 sB[128][LDT];

    const int tid  = threadIdx.x;
    const int bn   = blockIdx.x;
    const int bm   = blockIdx.y;
    const int row0 = bm * 128;
    const int col0 = bn * 128;

    const int lane = tid & 63;
    const int wid  = tid >> 6;
    const int wm   = (wid >> 1) * 64;
    const int wn   = (wid & 1) * 64;

    f32x4 acc[4][4];
    #pragma unroll
    for (int i = 0; i < 4; ++i)
        #pragma unroll
        for (int j = 0; j < 4; ++j)
            acc[i][j] = f32x4{0.f, 0.f, 0.f, 0.f};

    const int frow  = lane & 15;
    const int fkoff = (lane >> 4) * 8;

    for (int k0 = 0; k0 < 2048; k0 += 32) {
        #pragma unroll
        for (int i = 0; i < 2; ++i) {
            int q  = tid + i * 256;   // 0..511
            int r  = q >> 2;          // 0..127
            int c8 = (q & 3) * 8;     // 0..24
            *(bf16x8*)&sA[r][c8] = *(const bf16x8*)&A [(size_t)(row0 + r) * 2048 + k0 + c8];
            *(bf16x8*)&sB[r][c8] = *(const bf16x8*)&Wb[(size_t)(col0 + r) * 2048 + k0 + c8];
        }
        __syncthreads();

        bf16x8 a_f[4], b_f[4];
        #pragma unroll
        for (int f = 0; f < 4; ++f) {
            a_f[f] = *(const bf16x8*)&sA[wm + f * 16 + frow][fkoff];
            b_f[f] = *(const bf16x8*)&sB[wn + f * 16 + frow][fkoff];
        }
        #pragma unroll
        for (int fm = 0; fm < 4; ++fm)
            #pragma unroll
            for (int fn = 0; fn < 4; ++fn)
                acc[fm][fn] = __builtin_amdgcn_mfma_f32_16x16x32_bf16(a_f[fm], b_f[fn], acc[fm][fn], 0, 0, 0);
        __syncthreads();
    }

    const int crow = (lane >> 4) * 4;
    const int ccol = lane & 15;
    #pragma unroll
    for (int fm = 0; fm < 4; ++fm)
        #pragma unroll
        for (int fn = 0; fn < 4; ++fn)
            #pragma unroll
            for (int j = 0; j < 4; ++j) {
                int rg = row0 + wm + fm * 16 + crow + j;
                int cg = col0 + wn + fn * 16 + ccol;
                O[(size_t)rg * 1024 + cg] = tanhf(acc[fm][fn][j] + bias[cg]);
            }
}

// ---------------------------------------------------------------------------
extern "C" void kernel_launch(void* const* d_in, const int* in_sizes, int n_in,
                              void* d_out, int out_size, void* d_ws, size_t ws_size,
                              hipStream_t stream)
{
    const float* x     = (const float*)d_in[0];
    const float* W_in  = (const float*)d_in[1];
    const float* b_in  = (const float*)d_in[2];
    const float* leak  = (const float*)d_in[3];
    const float* thr   = (const float*)d_in[4];
    const float* W_out = (const float*)d_in[5];
    const float* b_out = (const float*)d_in[6];

    // ws: [0,64MiB) comb bf16 ; [64MiB, 64MiB+4MiB) Wb bf16
    const size_t NEED = (64ull << 20) + (4ull << 20);
    if (ws_size < NEED) return;

    float*  out  = (float*)d_out;   // also I scratch
    __bf16* comb = (__bf16*)d_ws;
    __bf16* Wb   = (__bf16*)((char*)d_ws + (64ull << 20));

    dim3 grid(8, 128);

    wcvt_kernel<<<1024, 256, 0, stream>>>(W_out, Wb);
    gemm1_f32chain_kernel<<<grid, 256, 0, stream>>>(x, W_in, b_in, out);
    hsru_scan_f32_kernel<<<256, 64, 0, stream>>>(out, leak, thr, comb);
    gemm2_kernel<<<grid, 256, 0, stream>>>(comb, Wb, b_out, out);
}